// Round 19
// baseline (494.792 us; speedup 1.0000x reference)
//
#include <hip/hip_runtime.h>
#include <hip/hip_bf16.h>
#include <math.h>

#define N_TOK 8192
#define DIM   1024
#define HID   2048
#define NE    8
#define NKS1  32     // DIM/32 stages (ffn1)
#define NKS2  64     // HID/32 stages (ffn2)
#define NB1   16     // HID/128 panels (ffn1)
#define NB2   4      // DIM/256 panels (ffn2)
#define MAXT  72     // max 256-row (e,m0) tiles
#define PANEL1_SH ((size_t)(128 * 256 * 8))   // shorts per ffn1 [W1|W2] panel (512KB)
#define PANEL3_SH ((size_t)(256 * 256 * 8))   // shorts per w3 256-col panel (1MB)
#define XBLK_SH   ((size_t)(128 * 128 * 8))   // shorts per 128-row Xg block (256KB)
#define HBLK_SH   ((size_t)(256 * 128 * 8))   // shorts per 128-row Hsw block (512KB)

typedef __attribute__((ext_vector_type(8))) short short8;
typedef __attribute__((ext_vector_type(4))) float f32x4;
typedef unsigned short us;

__device__ __forceinline__ us f2bf(float f) {
    unsigned int u = __builtin_bit_cast(unsigned int, f);
    unsigned int r = (u + 0x7fffu + ((u >> 16) & 1u)) >> 16;   // RNE
    return (us)r;
}
__device__ __forceinline__ float bf2f(us v) {
    unsigned int u = ((unsigned int)v) << 16;
    return __builtin_bit_cast(float, u);
}
__device__ __forceinline__ void gl_lds16(const us* g, us* l) {
    __builtin_amdgcn_global_load_lds(
        (const __attribute__((address_space(1))) void*)g,
        (__attribute__((address_space(3))) void*)l, 16, 0, 0);
}

#define VMW8 asm volatile("s_waitcnt vmcnt(8)" ::: "memory")
#define VMW4 asm volatile("s_waitcnt vmcnt(4)" ::: "memory")
#define VMW0 asm volatile("s_waitcnt vmcnt(0)" ::: "memory")
#define BARM asm volatile("s_barrier" ::: "memory")
#define PRIO1 __builtin_amdgcn_s_setprio(1)
#define PRIO0 __builtin_amdgcn_s_setprio(0)

// ---------------- gating phase A: logits/softmax/top2 + bf16 conversion of x ----------------
__global__ __launch_bounds__(256) void gate_compute(
    const float* __restrict__ x, const float* __restrict__ gw, const float* __restrict__ gb,
    int* __restrict__ sel, float2* __restrict__ wpair, float* __restrict__ usage_part,
    us* __restrict__ xb)
{
    const int lane = threadIdx.x & 63;
    const int tok = blockIdx.x * 4 + (threadIdx.x >> 6);

    __shared__ float su[NE];
    if (threadIdx.x < NE) su[threadIdx.x] = 0.f;
    __syncthreads();

    float acc[NE];
#pragma unroll
    for (int e = 0; e < NE; e++) acc[e] = 0.f;

    const float* xr = x + (size_t)tok * DIM;
    us* xbr = xb + (size_t)tok * DIM;
    for (int d = lane; d < DIM; d += 64) {
        float xv = xr[d];
        xbr[d] = f2bf(xv);
        const float4* g4 = (const float4*)(gw + (size_t)d * NE);
        float4 ga = g4[0], gc = g4[1];
        acc[0] = fmaf(xv, ga.x, acc[0]);
        acc[1] = fmaf(xv, ga.y, acc[1]);
        acc[2] = fmaf(xv, ga.z, acc[2]);
        acc[3] = fmaf(xv, ga.w, acc[3]);
        acc[4] = fmaf(xv, gc.x, acc[4]);
        acc[5] = fmaf(xv, gc.y, acc[5]);
        acc[6] = fmaf(xv, gc.z, acc[6]);
        acc[7] = fmaf(xv, gc.w, acc[7]);
    }
#pragma unroll
    for (int e = 0; e < NE; e++) {
#pragma unroll
        for (int off = 32; off > 0; off >>= 1)
            acc[e] += __shfl_xor(acc[e], off);
    }

    if (lane == 0) {
        float lg[NE], p[NE];
        float mx = -1e30f;
#pragma unroll
        for (int e = 0; e < NE; e++) { lg[e] = acc[e] + gb[e]; mx = fmaxf(mx, lg[e]); }
        float s = 0.f;
#pragma unroll
        for (int e = 0; e < NE; e++) { p[e] = __expf(lg[e] - mx); s += p[e]; }
        float inv = 1.f / s;
#pragma unroll
        for (int e = 0; e < NE; e++) p[e] *= inv;
#pragma unroll
        for (int e = 0; e < NE; e++) atomicAdd(&su[e], p[e]);   // LDS atomic only

        int e1 = 0; float v1 = p[0];
#pragma unroll
        for (int e = 1; e < NE; e++) if (p[e] > v1) { v1 = p[e]; e1 = e; }
        int e2 = -1; float v2 = -1e30f;
#pragma unroll
        for (int e = 0; e < NE; e++) if (e != e1 && p[e] > v2) { v2 = p[e]; e2 = e; }

        sel[tok] = e1 | (e2 << 4);
        wpair[tok] = make_float2(v1, v2);
    }
    __syncthreads();
    if (threadIdx.x < NE) usage_part[blockIdx.x * NE + threadIdx.x] = su[threadIdx.x];
}

// ---------------- gating phase B: deterministic counting-sort ----------------
__global__ __launch_bounds__(256) void scan_kernel(
    const int* __restrict__ sel, const float2* __restrict__ wpair,
    int* __restrict__ counts, int* __restrict__ lists, float* __restrict__ wlist)
{
    const int e = blockIdx.x;
    const int t = threadIdx.x;
    const int base_tok = t * 32;

    unsigned selm = 0, km = 0;
#pragma unroll
    for (int i = 0; i < 32; i++) {
        int s = sel[base_tok + i];
        int e1 = s & 15, e2 = (s >> 4) & 15;
        if (e1 == e) selm |= (1u << i);
        else if (e2 == e) { selm |= (1u << i); km |= (1u << i); }
    }
    const int myc = __popc(selm);

    __shared__ int tot[256];
    tot[t] = myc;
    __syncthreads();
#pragma unroll
    for (int d = 1; d < 256; d <<= 1) {
        int v = (t >= d) ? tot[t - d] : 0;
        __syncthreads();
        tot[t] += v;
        __syncthreads();
    }
    int pos = tot[t] - myc;
    if (t == 255) counts[e] = tot[255];

    for (int i = 0; i < 32; i++) {
        if (selm & (1u << i)) {
            int tok = base_tok + i;
            int k = (km >> i) & 1;
            lists[e * N_TOK + pos] = tok * 2 + k;
            float2 wp = wpair[tok];
            wlist[e * N_TOK + pos] = k ? wp.y : wp.x;
            pos++;
        }
    }
}

__global__ __launch_bounds__(256) void usage_reduce(
    const float* __restrict__ part, float* __restrict__ usage)
{
    const int t = threadIdx.x;
    const int e = t & 7, chunk = t >> 3;
    float s = 0.f;
    for (int b = chunk; b < 2048; b += 32) s += part[b * NE + e];
    __shared__ float red[256];
    red[t] = s;
    __syncthreads();
#pragma unroll
    for (int step = 128; step >= 8; step >>= 1) {
        if (t < step) red[t] += red[t + step];
        __syncthreads();
    }
    if (t < NE) usage[t] = red[t];
}

__global__ void loss_kernel(const float* __restrict__ usage, float* __restrict__ out_loss)
{
    if (threadIdx.x == 0) {
        float l = 0.f;
        for (int e = 0; e < NE; e++) {
            float u = usage[e] / (float)N_TOK;
            l += u * logf(u + 1e-9f);
        }
        *out_loss = l;
    }
}

__global__ void prefix_kernel(const int* __restrict__ counts,
                              int* __restrict__ base_exact, int* __restrict__ ntiles,
                              int* __restrict__ tmap_e, int* __restrict__ tmap_m0)
{
    if (threadIdx.x == 0) {
        int bx = 0, nt = 0;
        for (int e = 0; e < NE; e++) {
            base_exact[e] = bx;
            for (int m0 = 0; m0 < counts[e]; m0 += 256) {
                tmap_e[nt] = e; tmap_m0[nt] = m0; nt++;
            }
            bx += counts[e];
        }
        ntiles[0] = nt;
    }
}

__global__ __launch_bounds__(256) void inv_kernel(
    const int* __restrict__ counts, const int* __restrict__ lists,
    const int* __restrict__ base_exact, int* __restrict__ inv)
{
    const int e = blockIdx.y;
    const int idx = blockIdx.x * 256 + threadIdx.x;
    if (idx < counts[e]) inv[lists[e * N_TOK + idx]] = base_exact[e] + idx;
}

// ---------------- X pre-gather: Xbf -> Xg (routing order, chunk-tiled) ----------------
__global__ __launch_bounds__(256) void xgather_kernel(
    const us* __restrict__ Xbf,
    const int* __restrict__ counts, const int* __restrict__ lists,
    const int* __restrict__ base_exact,
    us* __restrict__ Xg)
{
    __shared__ int toks[128];
    __shared__ int bexs[NE], cnts[NE];
    const int t = threadIdx.x;
    if (t < NE) { bexs[t] = base_exact[t]; cnts[t] = counts[t]; }
    __syncthreads();
    if (t < 128) {
        int gpos = blockIdx.x * 128 + t;
        int e = 0;
#pragma unroll
        for (int k = 1; k < NE; k++) if (gpos >= bexs[k]) e = k;
        int idx = gpos - bexs[e];
        int tok = (idx < cnts[e]) ? (lists[e * N_TOK + idx] >> 1) : 0;
        toks[t] = tok;
    }
    __syncthreads();

    us* op = Xg + (size_t)blockIdx.x * XBLK_SH;
    const int rr = t & 127;
    const int ch = t >> 7;
    const us* srcrow = Xbf + (size_t)toks[rr] * DIM;
#pragma unroll
    for (int it = 0; it < 64; it++) {
        int c = it * 2 + ch;
        short8 v = *(const short8*)(srcrow + c * 8);
        *(short8*)(op + (size_t)(c * 128 + rr) * 8) = v;
    }
}

// ---------------- w1,w2 -> [e][nbx16][gk128][row256][8], rows = [W1 128 | W2 128] ----------------
__global__ __launch_bounds__(256) void wswz12_kernel(
    const float* __restrict__ w1, const float* __restrict__ w2, us* __restrict__ out)
{
    const int e = blockIdx.z, nbx = blockIdx.y, gs = blockIdx.x;
    us* op = out + ((size_t)e * NB1 + nbx) * PANEL1_SH + (size_t)gs * 8 * 256 * 8;
    const float* w1e = w1 + (size_t)e * DIM * HID;
    const float* w2e = w2 + (size_t)e * DIM * HID;
    const int t = threadIdx.x;
#pragma unroll
    for (int it = 0; it < 8; it++) {
        int idx = it * 256 + t;
        int g = idx >> 8, row = idx & 255;
        int col = nbx * 128 + (row & 127);
        const float* src = (row < 128 ? w1e : w2e) + (size_t)((gs * 8 + g) * 8) * HID + col;
        short8 v;
#pragma unroll
        for (int s = 0; s < 8; s++) v[s] = (short)f2bf(src[(size_t)s * HID]);
        *(short8*)(op + (size_t)idx * 8) = v;
    }
}

// ---------------- w3 -> [e][nbx4][gk256][row256][8] ----------------
__global__ __launch_bounds__(256) void wswz3_kernel(
    const float* __restrict__ w3, us* __restrict__ out)
{
    const int e = blockIdx.z, nbx = blockIdx.y, gs = blockIdx.x;
    us* op = out + ((size_t)e * NB2 + nbx) * PANEL3_SH + (size_t)gs * 8 * 256 * 8;
    const float* w3e = w3 + (size_t)e * HID * DIM;
    const int t = threadIdx.x;
#pragma unroll
    for (int it = 0; it < 8; it++) {
        int idx = it * 256 + t;
        int g = idx >> 8, row = idx & 255;
        int col = nbx * 256 + row;
        const float* src = w3e + (size_t)((gs * 8 + g) * 8) * DIM + col;
        short8 v;
#pragma unroll
        for (int s = 0; s < 8; s++) v[s] = (short)f2bf(src[(size_t)s * DIM]);
        *(short8*)(op + (size_t)idx * 8) = v;
    }
}

#define SA(s) ((us*)(SM + (s)*32768))
#define SB(s) ((us*)(SM + (s)*32768 + 16384))

#define CLUST32 do {                                                     \
    PRIO1;                                                               \
    _Pragma("unroll")                                                    \
    for (int j = 0; j < 4; j++) {                                        \
        _Pragma("unroll")                                                \
        for (int mi = 0; mi < 8; mi++)                                   \
            acc[mi][j] = __builtin_amdgcn_mfma_f32_16x16x32_bf16(        \
                af[mi], bfv[j], acc[mi][j], 0, 0, 0);                    \
    }                                                                    \
    PRIO0;                                                               \
} while (0)

#define FRAG_READ(s) do {                                                \
    _Pragma("unroll")                                                    \
    for (int mi = 0; mi < 8; mi++)                                       \
        af[mi] = *(const short8*)(SA(s) + (kc*256 + Mw + mi*16 + fr)*8); \
    _Pragma("unroll")                                                    \
    for (int j = 0; j < 4; j++)                                          \
        bfv[j] = *(const short8*)(SB(s) + (kc*256 + Nw + j*16 + fr)*8);  \
} while (0)

// ---------------- pass A: Xg @ [W1|W2] -> swiglu -> Hsw ----------------
// 256x256 tile, BK=32 stages, 4 LDS buffers, depth-3 counted-vmcnt pipeline.
__global__ __launch_bounds__(512, 2) void ffn1_mfma_kernel(
    const us* __restrict__ Xg, const us* __restrict__ W12sw,
    const float* __restrict__ b1, const float* __restrict__ b2,
    const int* __restrict__ counts, const int* __restrict__ base_exact,
    const int* __restrict__ ntiles, const int* __restrict__ tmap_e, const int* __restrict__ tmap_m0,
    us* __restrict__ Hsw)
{
    const int hw = blockIdx.x;
    const int ix = hw >> 3;
    const int nbx = ((hw & 7) << 1) | (ix & 1);      // XCD*2 + sub
    const int by  = ix >> 1;
    if (by >= ntiles[0]) return;
    const int e  = tmap_e[by];
    const int m0 = tmap_m0[by];
    const int cnt = counts[e];
    const int bex = base_exact[e];

    __shared__ __align__(16) unsigned char SM[132096];

    const int t = threadIdx.x;
    const int lane = t & 63, wv = t >> 6;
    const int wr = wv >> 2, wc = wv & 3;
    const int Mw = wr * 128, Nw = wc * 64;
    const int fr = lane & 15, kc = lane >> 4;

    float bb[4];
    {
        const float* bsrc = (wc < 2) ? b1 : b2;
#pragma unroll
        for (int ni = 0; ni < 4; ni++)
            bb[ni] = bsrc[e * HID + nbx * 128 + (wc & 1) * 64 + ni * 16 + fr];
    }
    __syncthreads();   // drain bias loads -> vmcnt 0 before counted pipeline

    // staging: thread t covers LDS chunks t and t+512 (same row, kq and kq+2)
    const int arow = t & 255;
    const int kq0  = t >> 8;                    // 0/1
    const int RA = min(bex + m0 + arow, N_TOK * 2 - 1);
    const us* ApR = Xg + (size_t)(RA >> 7) * XBLK_SH + (RA & 127) * 8;
    const us* Wp  = W12sw + ((size_t)e * NB1 + nbx) * PANEL1_SH;
    const int db0 = (t & ~63) * 8;
    const int db1 = db0 + 512 * 8;

    #define F1_STAGE(ks) do {                                                   \
        const int s_ = (ks) & 3;                                                \
        gl_lds16(ApR + (size_t)((ks)*4 + kq0)     * 1024, SA(s_) + db0);        \
        gl_lds16(ApR + (size_t)((ks)*4 + kq0 + 2) * 1024, SA(s_) + db1);        \
        gl_lds16(Wp + ((size_t)(ks)*1024 + t)       * 8,  SB(s_) + db0);        \
        gl_lds16(Wp + ((size_t)(ks)*1024 + t + 512) * 8,  SB(s_) + db1);        \
    } while (0)

    f32x4 acc[8][4];
    const f32x4 fz = {0.f, 0.f, 0.f, 0.f};
#pragma unroll
    for (int i = 0; i < 8; i++)
#pragma unroll
        for (int j = 0; j < 4; j++) acc[i][j] = fz;

    short8 af[8], bfv[4];

    F1_STAGE(0); F1_STAGE(1); F1_STAGE(2);
    VMW8; BARM;                                   // stage 0 complete & published

    for (int ks = 0; ks < NKS1; ++ks) {
        FRAG_READ(ks & 3);
        if (ks + 3 < NKS1)      { F1_STAGE(ks + 3); VMW8; }
        else if (ks == NKS1 - 3) { VMW4; }
        else if (ks == NKS1 - 2) { VMW0; }
        BARM;                                     // publish stage ks+1
        CLUST32;
        BARM;                                     // close iteration
    }
    #undef F1_STAGE

    // ---- SwiGLU epilogue via LDS gate exchange ----
    float* G = (float*)SM;
    if (wc >= 2) {
        const int cp = wc - 2;
#pragma unroll
        for (int ni = 0; ni < 4; ni++) {
            int c2 = cp * 64 + ni * 16 + fr;
#pragma unroll
            for (int mi = 0; mi < 8; mi++) {
#pragma unroll
                for (int j = 0; j < 4; j++) {
                    int m = mi * 16 + kc * 4 + j;
                    float g = 1.f / (1.f + __expf(-(acc[mi][ni][j] + bb[ni])));
                    G[(wr * 128 + c2) * 129 + m] = g;
                }
            }
        }
    }
    __syncthreads();
    if (wc < 2) {
#pragma unroll
        for (int ni = 0; ni < 4; ni++) {
            int c2 = wc * 64 + ni * 16 + fr;
            int ch = nbx * 128 + c2;
            size_t cb = (size_t)(ch >> 3) * 128 * 8 + (ch & 7);
#pragma unroll
            for (int mi = 0; mi < 8; mi++) {
#pragma unroll
                for (int j = 0; j < 4; j++) {
                    int m = mi * 16 + kc * 4 + j;
                    int rl = wr * 128 + m;
                    if (m0 + rl >= cnt) continue;
                    float h = (acc[mi][ni][j] + bb[ni]) * G[(wr * 128 + c2) * 129 + m];
                    int R = bex + m0 + rl;
                    Hsw[(size_t)(R >> 7) * HBLK_SH + cb + (size_t)(R & 127) * 8] = f2bf(h);
                }
            }
        }
    }
}

// ---------------- pass B: Hsw @ w3 -> bf16 partials Pb (deep pipeline) ----------------
__global__ __launch_bounds__(512, 2) void ffn2_mfma_kernel(
    const us* __restrict__ Hsw, const us* __restrict__ W3sw, const float* __restrict__ b3,
    const int* __restrict__ counts, const int* __restrict__ base_exact,
    const int* __restrict__ ntiles, const int* __restrict__ tmap_e, const int* __restrict__ tmap_m0,
    const float* __restrict__ wts,
    us* __restrict__ Pb)
{
    const int hw = blockIdx.x;
    const int xcd = hw & 7;
    const int ix = hw >> 3;
    const int nbx = xcd & 3;
    const int by = (ix << 1) | (xcd >> 2);
    if (by >= ntiles[0]) return;
    const int e  = tmap_e[by];
    const int m0 = tmap_m0[by];
    const int cnt = counts[e];
    const int bex = base_exact[e];

    __shared__ __align__(16) unsigned char SM[132096];
    float* rowwt = (float*)(SM + 131072);   // above the 4x32KB stage buffers

    const int t = threadIdx.x;
    if (t < 256) {
        int idx = m0 + t;
        rowwt[t] = (idx < cnt) ? wts[e * N_TOK + idx] : 0.f;
    }

    const int lane = t & 63, wv = t >> 6;
    const int wr = wv >> 2, wc = wv & 3;
    const int Mw = wr * 128, Nw = wc * 64;
    const int fr = lane & 15, kc = lane >> 4;

    float bb3[4];
#pragma unroll
    for (int ni = 0; ni < 4; ni++)
        bb3[ni] = b3[e * DIM + nbx * 256 + wc * 64 + ni * 16 + fr];
    __syncthreads();   // publish rowwt, drain vmcnt

    const int arow = t & 255;
    const int kq0  = t >> 8;
    const int RA = min(bex + m0 + arow, N_TOK * 2 - 1);
    const us* HpR = Hsw + (size_t)(RA >> 7) * HBLK_SH + (RA & 127) * 8;
    const us* Wp  = W3sw + ((size_t)e * NB2 + nbx) * PANEL3_SH;
    const int db0 = (t & ~63) * 8;
    const int db1 = db0 + 512 * 8;

    #define F2_STAGE(ks) do {                                                   \
        const int s_ = (ks) & 3;                                                \
        gl_lds16(HpR + (size_t)((ks)*4 + kq0)     * 1024, SA(s_) + db0);        \
        gl_lds16(HpR + (size_t)((ks)*4 + kq0 + 2) * 1024, SA(s_) + db1);        \
        gl_lds16(Wp + ((size_t)(ks)*1024 + t)       * 8,  SB(s_) + db0);        \
        gl_lds16(Wp + ((size_t)(ks)*1024 + t + 512) * 8,  SB(s_) + db1);        \
    } while (0)

    f32x4 acc[8][4];
    const f32x4 fz = {0.f, 0.f, 0.f, 0.f};
#pragma unroll
    for (int i = 0; i < 8; i++)
#pragma unroll
        for (int j = 0; j < 4; j++) acc[i][j] = fz;

    short8 af[8], bfv[4];

    F2_STAGE(0); F2_STAGE(1); F2_STAGE(2);
    VMW8; BARM;

    for (int ks = 0; ks < NKS2; ++ks) {
        FRAG_READ(ks & 3);
        if (ks + 3 < NKS2)      { F2_STAGE(ks + 3); VMW8; }
        else if (ks == NKS2 - 3) { VMW4; }
        else if (ks == NKS2 - 2) { VMW0; }
        BARM;
        CLUST32;
        BARM;
    }
    #undef F2_STAGE

#pragma unroll
    for (int ni = 0; ni < 4; ni++) {
        int col = nbx * 256 + wc * 64 + ni * 16 + fr;
#pragma unroll
        for (int mi = 0; mi < 8; mi++) {
#pragma unroll
            for (int j = 0; j < 4; j++) {
                int rl = wr * 128 + mi * 16 + kc * 4 + j;
                if (m0 + rl >= cnt) continue;
                float v = (acc[mi][ni][j] + bb3[ni]) * rowwt[rl];
                Pb[(size_t)(bex + m0 + rl) * DIM + col] = f2bf(v);
            }
        }
    }
}

// out[tok][c] = Pb[inv[2t]][c] + Pb[inv[2t+1]][c]
__global__ __launch_bounds__(256) void combine_kernel(
    const us* __restrict__ Pb, const int* __restrict__ inv,
    float* __restrict__ out)
{
    int gid = blockIdx.x * 256 + threadIdx.x;
    int tok = gid >> 7;
    int c8 = (gid & 127) * 8;
    const short8 a = *(const short8*)(Pb + (size_t)inv[tok * 2] * DIM + c8);
    const short8 b = *(const short8*)(Pb + (size_t)inv[tok * 2 + 1] * DIM + c8);
    float4 r0, r1;
    r0.x = bf2f((us)a[0]) + bf2f((us)b[0]);
    r0.y = bf2f((us)a[1]) + bf2f((us)b[1]);
    r0.z = bf2f((us)a[2]) + bf2f((us)b[2]);
    r0.w = bf2f((us)a[3]) + bf2f((us)b[3]);
    r1.x = bf2f((us)a[4]) + bf2f((us)b[4]);
    r1.y = bf2f((us)a[5]) + bf2f((us)b[5]);
    r1.z = bf2f((us)a[6]) + bf2f((us)b[6]);
    r1.w = bf2f((us)a[7]) + bf2f((us)b[7]);
    float* o = out + (size_t)tok * DIM + c8;
    *(float4*)o = r0;
    *(float4*)(o + 4) = r1;
}

extern "C" void kernel_launch(void* const* d_in, const int* in_sizes, int n_in,
                              void* d_out, int out_size, void* d_ws, size_t ws_size,
                              hipStream_t stream) {
    (void)in_sizes; (void)n_in; (void)out_size; (void)ws_size;
    const float* x      = (const float*)d_in[0];
    const float* gate_w = (const float*)d_in[1];
    const float* gate_b = (const float*)d_in[2];
    const float* w1     = (const float*)d_in[3];
    const float* b1     = (const float*)d_in[4];
    const float* w2     = (const float*)d_in[5];
    const float* b2     = (const float*)d_in[6];
    const float* w3     = (const float*)d_in[7];
    const float* b3     = (const float*)d_in[8];
    float* out = (float*)d_out;

    char* ws = (char*)d_ws;
    float* usage      = (float*)ws;
    int*   counts     = (int*)(ws + 32);
    int*   base_exact = (int*)(ws + 64);
    int*   ntiles     = (int*)(ws + 96);
    int*   tmap_e     = (int*)(ws + 128);
    int*   tmap_m0    = (int*)(ws + 640);
    int*   lists      = (int*)(ws + 4096);                        // 256 KB
    float* wts        = (float*)(ws + 4096 + (size_t)NE * N_TOK * 4);   // 256 KB
    int*   inv        = (int*)(ws + 4096 + (size_t)2 * NE * N_TOK * 4); // 64 KB
    int*   sel        = (int*)(ws + 4096 + 576 * 1024);           // 32 KB
    float2* wpair     = (float2*)(ws + 4096 + 608 * 1024);        // 64 KB
    float* usage_part = (float*)(ws + 4096 + 672 * 1024);         // 64 KB
    us* Hsw   = (us*)(ws + (1ull  << 20));                        // @1 MiB, 64 MiB
    us* W12sw = (us*)(ws + (65ull << 20));                        // @65 MiB, 64 MiB (ffn1 phase)
    us* W3sw  = W12sw;                                            // @65 MiB, 32 MiB (ffn2 phase)
    us* Pb    = (us*)(ws + (97ull << 20));                        // @97 MiB, 32 MiB bf16 partials
    us* Xbf   = (us*)(ws + (65ull << 20));                        // @65 MiB, 16 MiB (prep; dead before wswz12)
    us* Xg    = (us*)d_out;                                       // 32 MiB, routing-order X

    gate_compute<<<N_TOK / 4, 256, 0, stream>>>(x, gate_w, gate_b, sel, wpair, usage_part, Xbf);
    scan_kernel<<<NE, 256, 0, stream>>>(sel, wpair, counts, lists, wts);
    usage_reduce<<<1, 256, 0, stream>>>(usage_part, usage);
    prefix_kernel<<<1, 64, 0, stream>>>(counts, base_exact, ntiles, tmap_e, tmap_m0);
    {
        dim3 gI(N_TOK / 256, NE);
        inv_kernel<<<gI, 256, 0, stream>>>(counts, lists, base_exact, inv);
    }
    xgather_kernel<<<N_TOK * 2 / 128, 256, 0, stream>>>(Xbf, counts, lists, base_exact, Xg);

    dim3 gW12(16, NB1, NE);
    wswz12_kernel<<<gW12, 256, 0, stream>>>(w1, w2, W12sw);

    ffn1_mfma_kernel<<<NB1 * MAXT, 512, 0, stream>>>(Xg, W12sw, b1, b2, counts, base_exact,
                                                     ntiles, tmap_e, tmap_m0, Hsw);

    loss_kernel<<<1, 64, 0, stream>>>(usage, out + (size_t)N_TOK * DIM);

    dim3 gW3(32, NB2, NE);
    wswz3_kernel<<<gW3, 256, 0, stream>>>(w3, W3sw);

    ffn2_mfma_kernel<<<4 * MAXT, 512, 0, stream>>>(Hsw, W3sw, b3, counts, base_exact,
                                                   ntiles, tmap_e, tmap_m0, wts, Pb);
    combine_kernel<<<N_TOK * 128 / 256, 256, 0, stream>>>(Pb, inv, out);
}

// Round 20
// 487.626 us; speedup vs baseline: 1.0147x; 1.0147x over previous
//
#include <hip/hip_runtime.h>
#include <hip/hip_bf16.h>
#include <math.h>

#define N_TOK 8192
#define DIM   1024
#define HID   2048
#define NE    8
#define NT1   16     // DIM/64 K-tiles (ffn1)
#define NT2   32     // HID/64 K-tiles (ffn2)
#define NB1   16     // HID/128 panels (ffn1)
#define NB2   4      // DIM/256 panels (ffn2)
#define MAXT  72     // max 256-row (e,m0) tiles
#define PANEL1_SH ((size_t)(128 * 256 * 8))   // shorts per ffn1 [W1|W2] panel (512KB)
#define PANEL3_SH ((size_t)(256 * 256 * 8))   // shorts per w3 256-col panel (1MB)
#define XBLK_SH   ((size_t)(128 * 128 * 8))   // shorts per 128-row Xg block (256KB)
#define HBLK_SH   ((size_t)(256 * 128 * 8))   // shorts per 128-row Hsw block (512KB)

typedef __attribute__((ext_vector_type(8))) short short8;
typedef __attribute__((ext_vector_type(4))) float f32x4;
typedef unsigned short us;

__device__ __forceinline__ us f2bf(float f) {
    unsigned int u = __builtin_bit_cast(unsigned int, f);
    unsigned int r = (u + 0x7fffu + ((u >> 16) & 1u)) >> 16;   // RNE
    return (us)r;
}
__device__ __forceinline__ float bf2f(us v) {
    unsigned int u = ((unsigned int)v) << 16;
    return __builtin_bit_cast(float, u);
}
__device__ __forceinline__ void gl_lds16(const us* g, us* l) {
    __builtin_amdgcn_global_load_lds(
        (const __attribute__((address_space(1))) void*)g,
        (__attribute__((address_space(3))) void*)l, 16, 0, 0);
}

#define VMW4 asm volatile("s_waitcnt vmcnt(4)" ::: "memory")
#define VMW0 asm volatile("s_waitcnt vmcnt(0)" ::: "memory")
#define BARM asm volatile("s_barrier" ::: "memory")
#define PRIO1 __builtin_amdgcn_s_setprio(1)
#define PRIO0 __builtin_amdgcn_s_setprio(0)

// ---------------- gating phase A: logits/softmax/top2 + bf16 conversion of x ----------------
__global__ __launch_bounds__(256) void gate_compute(
    const float* __restrict__ x, const float* __restrict__ gw, const float* __restrict__ gb,
    int* __restrict__ sel, float2* __restrict__ wpair, float* __restrict__ usage_part,
    us* __restrict__ xb)
{
    const int lane = threadIdx.x & 63;
    const int tok = blockIdx.x * 4 + (threadIdx.x >> 6);

    __shared__ float su[NE];
    if (threadIdx.x < NE) su[threadIdx.x] = 0.f;
    __syncthreads();

    float acc[NE];
#pragma unroll
    for (int e = 0; e < NE; e++) acc[e] = 0.f;

    const float* xr = x + (size_t)tok * DIM;
    us* xbr = xb + (size_t)tok * DIM;
    for (int d = lane; d < DIM; d += 64) {
        float xv = xr[d];
        xbr[d] = f2bf(xv);                       // fused x->bf16 (x read once)
        const float4* g4 = (const float4*)(gw + (size_t)d * NE);
        float4 ga = g4[0], gc = g4[1];
        acc[0] = fmaf(xv, ga.x, acc[0]);
        acc[1] = fmaf(xv, ga.y, acc[1]);
        acc[2] = fmaf(xv, ga.z, acc[2]);
        acc[3] = fmaf(xv, ga.w, acc[3]);
        acc[4] = fmaf(xv, gc.x, acc[4]);
        acc[5] = fmaf(xv, gc.y, acc[5]);
        acc[6] = fmaf(xv, gc.z, acc[6]);
        acc[7] = fmaf(xv, gc.w, acc[7]);
    }
#pragma unroll
    for (int e = 0; e < NE; e++) {
#pragma unroll
        for (int off = 32; off > 0; off >>= 1)
            acc[e] += __shfl_xor(acc[e], off);
    }

    if (lane == 0) {
        float lg[NE], p[NE];
        float mx = -1e30f;
#pragma unroll
        for (int e = 0; e < NE; e++) { lg[e] = acc[e] + gb[e]; mx = fmaxf(mx, lg[e]); }
        float s = 0.f;
#pragma unroll
        for (int e = 0; e < NE; e++) { p[e] = __expf(lg[e] - mx); s += p[e]; }
        float inv = 1.f / s;
#pragma unroll
        for (int e = 0; e < NE; e++) p[e] *= inv;
#pragma unroll
        for (int e = 0; e < NE; e++) atomicAdd(&su[e], p[e]);   // LDS atomic only

        int e1 = 0; float v1 = p[0];
#pragma unroll
        for (int e = 1; e < NE; e++) if (p[e] > v1) { v1 = p[e]; e1 = e; }
        int e2 = -1; float v2 = -1e30f;
#pragma unroll
        for (int e = 0; e < NE; e++) if (e != e1 && p[e] > v2) { v2 = p[e]; e2 = e; }

        sel[tok] = e1 | (e2 << 4);
        wpair[tok] = make_float2(v1, v2);
    }
    __syncthreads();
    if (threadIdx.x < NE) usage_part[blockIdx.x * NE + threadIdx.x] = su[threadIdx.x];
}

// ---------------- gating phase B: deterministic counting-sort ----------------
__global__ __launch_bounds__(256) void scan_kernel(
    const int* __restrict__ sel, const float2* __restrict__ wpair,
    int* __restrict__ counts, int* __restrict__ lists, float* __restrict__ wlist)
{
    const int e = blockIdx.x;
    const int t = threadIdx.x;
    const int base_tok = t * 32;

    unsigned selm = 0, km = 0;
#pragma unroll
    for (int i = 0; i < 32; i++) {
        int s = sel[base_tok + i];
        int e1 = s & 15, e2 = (s >> 4) & 15;
        if (e1 == e) selm |= (1u << i);
        else if (e2 == e) { selm |= (1u << i); km |= (1u << i); }
    }
    const int myc = __popc(selm);

    __shared__ int tot[256];
    tot[t] = myc;
    __syncthreads();
#pragma unroll
    for (int d = 1; d < 256; d <<= 1) {
        int v = (t >= d) ? tot[t - d] : 0;
        __syncthreads();
        tot[t] += v;
        __syncthreads();
    }
    int pos = tot[t] - myc;
    if (t == 255) counts[e] = tot[255];

    for (int i = 0; i < 32; i++) {
        if (selm & (1u << i)) {
            int tok = base_tok + i;
            int k = (km >> i) & 1;
            lists[e * N_TOK + pos] = tok * 2 + k;
            float2 wp = wpair[tok];
            wlist[e * N_TOK + pos] = k ? wp.y : wp.x;
            pos++;
        }
    }
}

// usage tree-sum + load-balance loss, single launch
__global__ __launch_bounds__(256) void usage_loss_kernel(
    const float* __restrict__ part, float* __restrict__ out_loss)
{
    const int t = threadIdx.x;
    const int e = t & 7, chunk = t >> 3;
    float s = 0.f;
    for (int b = chunk; b < 2048; b += 32) s += part[b * NE + e];
    __shared__ float red[256];
    red[t] = s;
    __syncthreads();
#pragma unroll
    for (int step = 128; step >= 8; step >>= 1) {
        if (t < step) red[t] += red[t + step];
        __syncthreads();
    }
    if (t == 0) {
        float l = 0.f;
        for (int k = 0; k < NE; k++) {
            float u = red[k] / (float)N_TOK;
            l += u * logf(u + 1e-9f);
        }
        *out_loss = l;
    }
}

__global__ void prefix_kernel(const int* __restrict__ counts,
                              int* __restrict__ base_exact, int* __restrict__ ntiles,
                              int* __restrict__ tmap_e, int* __restrict__ tmap_m0)
{
    if (threadIdx.x == 0) {
        int bx = 0, nt = 0;
        for (int e = 0; e < NE; e++) {
            base_exact[e] = bx;
            for (int m0 = 0; m0 < counts[e]; m0 += 256) {
                tmap_e[nt] = e; tmap_m0[nt] = m0; nt++;
            }
            bx += counts[e];
        }
        ntiles[0] = nt;
    }
}

// ---------------- X pre-gather (+ fused inverse-index build) ----------------
__global__ __launch_bounds__(256) void xgather_kernel(
    const us* __restrict__ Xbf,
    const int* __restrict__ counts, const int* __restrict__ lists,
    const int* __restrict__ base_exact,
    us* __restrict__ Xg, int* __restrict__ inv)
{
    __shared__ int toks[128];
    __shared__ int bexs[NE], cnts[NE];
    const int t = threadIdx.x;
    if (t < NE) { bexs[t] = base_exact[t]; cnts[t] = counts[t]; }
    __syncthreads();
    if (t < 128) {
        int gpos = blockIdx.x * 128 + t;
        int e = 0;
#pragma unroll
        for (int k = 1; k < NE; k++) if (gpos >= bexs[k]) e = k;
        int idx = gpos - bexs[e];
        int tok = 0;
        if (idx < cnts[e]) {
            int rid = lists[e * N_TOK + idx];
            inv[rid] = gpos;                 // fused inv build (each valid rid once)
            tok = rid >> 1;
        }
        toks[t] = tok;
    }
    __syncthreads();

    us* op = Xg + (size_t)blockIdx.x * XBLK_SH;
    const int rr = t & 127;
    const int ch = t >> 7;
    const us* srcrow = Xbf + (size_t)toks[rr] * DIM;
#pragma unroll
    for (int it = 0; it < 64; it++) {
        int c = it * 2 + ch;
        short8 v = *(const short8*)(srcrow + c * 8);
        *(short8*)(op + (size_t)(c * 128 + rr) * 8) = v;
    }
}

// ---------------- w1,w2 -> [e][nbx16][gk128][row256][8], rows = [W1 128 | W2 128] ----------------
__global__ __launch_bounds__(256) void wswz12_kernel(
    const float* __restrict__ w1, const float* __restrict__ w2, us* __restrict__ out)
{
    const int e = blockIdx.z, nbx = blockIdx.y, gs = blockIdx.x;
    us* op = out + ((size_t)e * NB1 + nbx) * PANEL1_SH + (size_t)gs * 8 * 256 * 8;
    const float* w1e = w1 + (size_t)e * DIM * HID;
    const float* w2e = w2 + (size_t)e * DIM * HID;
    const int t = threadIdx.x;
#pragma unroll
    for (int it = 0; it < 8; it++) {
        int idx = it * 256 + t;
        int g = idx >> 8, row = idx & 255;
        int col = nbx * 128 + (row & 127);
        const float* src = (row < 128 ? w1e : w2e) + (size_t)((gs * 8 + g) * 8) * HID + col;
        short8 v;
#pragma unroll
        for (int s = 0; s < 8; s++) v[s] = (short)f2bf(src[(size_t)s * HID]);
        *(short8*)(op + (size_t)idx * 8) = v;
    }
}

// ---------------- w3 -> [e][nbx4][gk256][row256][8] ----------------
__global__ __launch_bounds__(256) void wswz3_kernel(
    const float* __restrict__ w3, us* __restrict__ out)
{
    const int e = blockIdx.z, nbx = blockIdx.y, gs = blockIdx.x;
    us* op = out + ((size_t)e * NB2 + nbx) * PANEL3_SH + (size_t)gs * 8 * 256 * 8;
    const float* w3e = w3 + (size_t)e * HID * DIM;
    const int t = threadIdx.x;
#pragma unroll
    for (int it = 0; it < 8; it++) {
        int idx = it * 256 + t;
        int g = idx >> 8, row = idx & 255;
        int col = nbx * 256 + row;
        const float* src = w3e + (size_t)((gs * 8 + g) * 8) * DIM + col;
        short8 v;
#pragma unroll
        for (int s = 0; s < 8; s++) v[s] = (short)f2bf(src[(size_t)s * DIM]);
        *(short8*)(op + (size_t)idx * 8) = v;
    }
}

#define ABUF(b) ((us*)(SM + (b)*32768))
#define BBUF(b) ((us*)(SM + 65536 + (b)*32768))

#define AF_READ(b, h) do {                                               \
    _Pragma("unroll")                                                    \
    for (int mi = 0; mi < 8; mi++)                                       \
        af[mi] = *(const short8*)(ABUF(b) + ((h)*1024 + kc*256 + Mw + mi*16 + fr)*8); \
} while (0)
#define BF_READ4(b, h) do {                                              \
    _Pragma("unroll")                                                    \
    for (int j = 0; j < 4; j++)                                          \
        bfv[j] = *(const short8*)(BBUF(b) + ((h)*1024 + kc*256 + Nw + j*16 + fr)*8); \
} while (0)
#define CLUST4 do {                                                      \
    PRIO1;                                                               \
    _Pragma("unroll")                                                    \
    for (int j = 0; j < 4; j++) {                                        \
        _Pragma("unroll")                                                \
        for (int mi = 0; mi < 8; mi++)                                   \
            acc[mi][j] = __builtin_amdgcn_mfma_f32_16x16x32_bf16(        \
                af[mi], bfv[j], acc[mi][j], 0, 0, 0);                    \
    }                                                                    \
    PRIO0;                                                               \
} while (0)

// ---------------- pass A: Xg @ [W1|W2] -> swiglu -> Hsw ----------------
__global__ __launch_bounds__(512, 2) void ffn1_mfma_kernel(
    const us* __restrict__ Xg, const us* __restrict__ W12sw,
    const float* __restrict__ b1, const float* __restrict__ b2,
    const int* __restrict__ counts, const int* __restrict__ base_exact,
    const int* __restrict__ ntiles, const int* __restrict__ tmap_e, const int* __restrict__ tmap_m0,
    us* __restrict__ Hsw)
{
    const int hw = blockIdx.x;
    const int ix = hw >> 3;
    const int nbx = ((hw & 7) << 1) | (ix & 1);      // XCD*2 + sub
    const int by  = ix >> 1;
    if (by >= ntiles[0]) return;
    const int e  = tmap_e[by];
    const int m0 = tmap_m0[by];
    const int cnt = counts[e];
    const int bex = base_exact[e];

    __shared__ __align__(16) unsigned char SM[132096];

    const int t = threadIdx.x;
    const int lane = t & 63, wv = t >> 6;
    const int wr = wv >> 2, wc = wv & 3;
    const int Mw = wr * 128, Nw = wc * 64;
    const int fr = lane & 15, kc = lane >> 4;

    float bb[4];
    {
        const float* bsrc = (wc < 2) ? b1 : b2;
#pragma unroll
        for (int ni = 0; ni < 4; ni++)
            bb[ni] = bsrc[e * HID + nbx * 128 + (wc & 1) * 64 + ni * 16 + fr];
    }
    __syncthreads();

    const int c0 = wv * 128 + lane;
    const int c1 = c0 + 64;
    const int RA0 = min(bex + m0 + (c0 & 255), N_TOK * 2 - 1);
    const int RA1 = min(bex + m0 + (c1 & 255), N_TOK * 2 - 1);
    const us* ApA = Xg + (size_t)(RA0 >> 7) * XBLK_SH + (size_t)(c0 >> 8) * 1024 + (RA0 & 127) * 8;
    const us* ApB = Xg + (size_t)(RA1 >> 7) * XBLK_SH + (size_t)(c1 >> 8) * 1024 + (RA1 & 127) * 8;
    const us* Wp = W12sw + ((size_t)e * NB1 + nbx) * PANEL1_SH;
    const int dbase = wv * 128 * 8;

    f32x4 acc[8][4];
    const f32x4 fz = {0.f, 0.f, 0.f, 0.f};
#pragma unroll
    for (int i = 0; i < 8; i++)
#pragma unroll
        for (int j = 0; j < 4; j++) acc[i][j] = fz;

    #define STAGE_A(b, tile, h) do {                                             \
        gl_lds16(ApA + (size_t)((tile)*8 + (h)*4) * 1024, ABUF(b) + ((h)*1024)*8 + dbase); \
        gl_lds16(ApB + (size_t)((tile)*8 + (h)*4) * 1024, ABUF(b) + ((h)*1024 + 64)*8 + dbase); \
    } while (0)
    #define STAGE_B(b, tile, h) do {                                             \
        const us* s_ = Wp + ((size_t)(tile)*2048 + (h)*1024) * 8;                \
        gl_lds16(s_ + (size_t)c0 * 8, BBUF(b) + ((h)*1024)*8 + dbase);           \
        gl_lds16(s_ + (size_t)c1 * 8, BBUF(b) + ((h)*1024 + 64)*8 + dbase);      \
    } while (0)

    short8 af[8], bfv[4];

    STAGE_A(0, 0, 0); STAGE_B(0, 0, 0); STAGE_A(0, 0, 1); STAGE_B(0, 0, 1);
    VMW4; BARM;

    for (int tl = 0; tl < NT1; ++tl) {
        const int b = tl & 1, nb = b ^ 1;
        const bool more = (tl + 1 < NT1);
        AF_READ(b, 0); BF_READ4(b, 0);
        if (more) { STAGE_A(nb, tl + 1, 0); STAGE_B(nb, tl + 1, 0); VMW4; } else { VMW0; }
        BARM; CLUST4; BARM;
        AF_READ(b, 1); BF_READ4(b, 1);
        if (more) { STAGE_A(nb, tl + 1, 1); STAGE_B(nb, tl + 1, 1); VMW4; }
        BARM; CLUST4; BARM;
    }
    #undef STAGE_A
    #undef STAGE_B

    // ---- SwiGLU epilogue via LDS gate exchange ----
    float* G = (float*)SM;
    if (wc >= 2) {
        const int cp = wc - 2;
#pragma unroll
        for (int ni = 0; ni < 4; ni++) {
            int c2 = cp * 64 + ni * 16 + fr;
#pragma unroll
            for (int mi = 0; mi < 8; mi++) {
#pragma unroll
                for (int j = 0; j < 4; j++) {
                    int m = mi * 16 + kc * 4 + j;
                    float g = 1.f / (1.f + __expf(-(acc[mi][ni][j] + bb[ni])));
                    G[(wr * 128 + c2) * 129 + m] = g;
                }
            }
        }
    }
    __syncthreads();
    if (wc < 2) {
#pragma unroll
        for (int ni = 0; ni < 4; ni++) {
            int c2 = wc * 64 + ni * 16 + fr;
            int ch = nbx * 128 + c2;
            size_t cb = (size_t)(ch >> 3) * 128 * 8 + (ch & 7);
#pragma unroll
            for (int mi = 0; mi < 8; mi++) {
#pragma unroll
                for (int j = 0; j < 4; j++) {
                    int m = mi * 16 + kc * 4 + j;
                    int rl = wr * 128 + m;
                    if (m0 + rl >= cnt) continue;
                    float h = (acc[mi][ni][j] + bb[ni]) * G[(wr * 128 + c2) * 129 + m];
                    int R = bex + m0 + rl;
                    Hsw[(size_t)(R >> 7) * HBLK_SH + cb + (size_t)(R & 127) * 8] = f2bf(h);
                }
            }
        }
    }
}

// ---------------- pass B: Hsw @ w3 -> bf16 partials Pb (single pass) ----------------
__global__ __launch_bounds__(512, 2) void ffn2_mfma_kernel(
    const us* __restrict__ Hsw, const us* __restrict__ W3sw, const float* __restrict__ b3,
    const int* __restrict__ counts, const int* __restrict__ base_exact,
    const int* __restrict__ ntiles, const int* __restrict__ tmap_e, const int* __restrict__ tmap_m0,
    const float* __restrict__ wts,
    us* __restrict__ Pb)
{
    const int hw = blockIdx.x;
    const int xcd = hw & 7;
    const int ix = hw >> 3;
    const int nbx = xcd & 3;
    const int by = (ix << 1) | (xcd >> 2);
    if (by >= ntiles[0]) return;
    const int e  = tmap_e[by];
    const int m0 = tmap_m0[by];
    const int cnt = counts[e];
    const int bex = base_exact[e];

    __shared__ __align__(16) unsigned char SM[132096];
    float* rowwt = (float*)(SM + 131072);

    const int t = threadIdx.x;
    if (t < 256) {
        int idx = m0 + t;
        rowwt[t] = (idx < cnt) ? wts[e * N_TOK + idx] : 0.f;
    }

    const int lane = t & 63, wv = t >> 6;
    const int wr = wv >> 2, wc = wv & 3;
    const int Mw = wr * 128, Nw = wc * 64;
    const int fr = lane & 15, kc = lane >> 4;

    float bb3[4];
#pragma unroll
    for (int ni = 0; ni < 4; ni++)
        bb3[ni] = b3[e * DIM + nbx * 256 + wc * 64 + ni * 16 + fr];
    __syncthreads();

    const int c0 = wv * 128 + lane;
    const int c1 = c0 + 64;
    const int RA0 = min(bex + m0 + (c0 & 255), N_TOK * 2 - 1);
    const int RA1 = min(bex + m0 + (c1 & 255), N_TOK * 2 - 1);
    const us* HpA = Hsw + (size_t)(RA0 >> 7) * HBLK_SH + (size_t)(c0 >> 8) * 1024 + (RA0 & 127) * 8;
    const us* HpB = Hsw + (size_t)(RA1 >> 7) * HBLK_SH + (size_t)(c1 >> 8) * 1024 + (RA1 & 127) * 8;
    const us* Wp = W3sw + ((size_t)e * NB2 + nbx) * PANEL3_SH;
    const int dbase = wv * 128 * 8;

    f32x4 acc[8][4];
    const f32x4 fz = {0.f, 0.f, 0.f, 0.f};
#pragma unroll
    for (int i = 0; i < 8; i++)
#pragma unroll
        for (int j = 0; j < 4; j++) acc[i][j] = fz;

    #define STAGE_A2(b, tile, h) do {                                            \
        gl_lds16(HpA + (size_t)((tile)*8 + (h)*4) * 1024, ABUF(b) + ((h)*1024)*8 + dbase); \
        gl_lds16(HpB + (size_t)((tile)*8 + (h)*4) * 1024, ABUF(b) + ((h)*1024 + 64)*8 + dbase); \
    } while (0)
    #define STAGE_B2(b, tile, h) do {                                            \
        const us* s_ = Wp + ((size_t)(tile)*2048 + (h)*1024) * 8;                \
        gl_lds16(s_ + (size_t)c0 * 8, BBUF(b) + ((h)*1024)*8 + dbase);           \
        gl_lds16(s_ + (size_t)c1 * 8, BBUF(b) + ((h)*1024 + 64)*8 + dbase);      \
    } while (0)

    short8 af[8], bfv[4];

    STAGE_A2(0, 0, 0); STAGE_B2(0, 0, 0); STAGE_A2(0, 0, 1); STAGE_B2(0, 0, 1);
    VMW4; BARM;

    for (int tl = 0; tl < NT2; ++tl) {
        const int b = tl & 1, nb = b ^ 1;
        const bool more = (tl + 1 < NT2);
        AF_READ(b, 0); BF_READ4(b, 0);
        if (more) { STAGE_A2(nb, tl + 1, 0); STAGE_B2(nb, tl + 1, 0); VMW4; } else { VMW0; }
        BARM; CLUST4; BARM;
        AF_READ(b, 1); BF_READ4(b, 1);
        if (more) { STAGE_A2(nb, tl + 1, 1); STAGE_B2(nb, tl + 1, 1); VMW4; }
        BARM; CLUST4; BARM;
    }
    #undef STAGE_A2
    #undef STAGE_B2

#pragma unroll
    for (int ni = 0; ni < 4; ni++) {
        int col = nbx * 256 + wc * 64 + ni * 16 + fr;
#pragma unroll
        for (int mi = 0; mi < 8; mi++) {
#pragma unroll
            for (int j = 0; j < 4; j++) {
                int rl = wr * 128 + mi * 16 + kc * 4 + j;
                if (m0 + rl >= cnt) continue;
                float v = (acc[mi][ni][j] + bb3[ni]) * rowwt[rl];
                Pb[(size_t)(bex + m0 + rl) * DIM + col] = f2bf(v);
            }
        }
    }
}

// out[tok][c] = Pb[inv[2t]][c] + Pb[inv[2t+1]][c]
__global__ __launch_bounds__(256) void combine_kernel(
    const us* __restrict__ Pb, const int* __restrict__ inv,
    float* __restrict__ out)
{
    int gid = blockIdx.x * 256 + threadIdx.x;
    int tok = gid >> 7;
    int c8 = (gid & 127) * 8;
    const short8 a = *(const short8*)(Pb + (size_t)inv[tok * 2] * DIM + c8);
    const short8 b = *(const short8*)(Pb + (size_t)inv[tok * 2 + 1] * DIM + c8);
    float4 r0, r1;
    r0.x = bf2f((us)a[0]) + bf2f((us)b[0]);
    r0.y = bf2f((us)a[1]) + bf2f((us)b[1]);
    r0.z = bf2f((us)a[2]) + bf2f((us)b[2]);
    r0.w = bf2f((us)a[3]) + bf2f((us)b[3]);
    r1.x = bf2f((us)a[4]) + bf2f((us)b[4]);
    r1.y = bf2f((us)a[5]) + bf2f((us)b[5]);
    r1.z = bf2f((us)a[6]) + bf2f((us)b[6]);
    r1.w = bf2f((us)a[7]) + bf2f((us)b[7]);
    float* o = out + (size_t)tok * DIM + c8;
    *(float4*)o = r0;
    *(float4*)(o + 4) = r1;
}

extern "C" void kernel_launch(void* const* d_in, const int* in_sizes, int n_in,
                              void* d_out, int out_size, void* d_ws, size_t ws_size,
                              hipStream_t stream) {
    (void)in_sizes; (void)n_in; (void)out_size; (void)ws_size;
    const float* x      = (const float*)d_in[0];
    const float* gate_w = (const float*)d_in[1];
    const float* gate_b = (const float*)d_in[2];
    const float* w1     = (const float*)d_in[3];
    const float* b1     = (const float*)d_in[4];
    const float* w2     = (const float*)d_in[5];
    const float* b2     = (const float*)d_in[6];
    const float* w3     = (const float*)d_in[7];
    const float* b3     = (const float*)d_in[8];
    float* out = (float*)d_out;

    char* ws = (char*)d_ws;
    int*   counts     = (int*)(ws + 32);
    int*   base_exact = (int*)(ws + 64);
    int*   ntiles     = (int*)(ws + 96);
    int*   tmap_e     = (int*)(ws + 128);
    int*   tmap_m0    = (int*)(ws + 640);
    int*   lists      = (int*)(ws + 4096);                        // 256 KB
    float* wts        = (float*)(ws + 4096 + (size_t)NE * N_TOK * 4);   // 256 KB
    int*   inv        = (int*)(ws + 4096 + (size_t)2 * NE * N_TOK * 4); // 64 KB
    int*   sel        = (int*)(ws + 4096 + 576 * 1024);           // 32 KB
    float2* wpair     = (float2*)(ws + 4096 + 608 * 1024);        // 64 KB
    float* usage_part = (float*)(ws + 4096 + 672 * 1024);         // 64 KB
    us* Hsw   = (us*)(ws + (1ull  << 20));                        // @1 MiB, 64 MiB
    us* W12sw = (us*)(ws + (65ull << 20));                        // @65 MiB, 64 MiB (ffn1 phase)
    us* W3sw  = W12sw;                                            // @65 MiB, 32 MiB (ffn2 phase)
    us* Pb    = (us*)(ws + (97ull << 20));                        // @97 MiB, 32 MiB bf16 partials
    us* Xbf   = (us*)(ws + (65ull << 20));                        // @65 MiB, 16 MiB (prep; dead before wswz12)
    us* Xg    = (us*)d_out;                                       // 32 MiB, routing-order X

    gate_compute<<<N_TOK / 4, 256, 0, stream>>>(x, gate_w, gate_b, sel, wpair, usage_part, Xbf);
    scan_kernel<<<NE, 256, 0, stream>>>(sel, wpair, counts, lists, wts);
    usage_loss_kernel<<<1, 256, 0, stream>>>(usage_part, out + (size_t)N_TOK * DIM);
    prefix_kernel<<<1, 64, 0, stream>>>(counts, base_exact, ntiles, tmap_e, tmap_m0);
    xgather_kernel<<<N_TOK * 2 / 128, 256, 0, stream>>>(Xbf, counts, lists, base_exact, Xg, inv);

    dim3 gW12(16, NB1, NE);
    wswz12_kernel<<<gW12, 256, 0, stream>>>(w1, w2, W12sw);

    ffn1_mfma_kernel<<<NB1 * MAXT, 512, 0, stream>>>(Xg, W12sw, b1, b2, counts, base_exact,
                                                     ntiles, tmap_e, tmap_m0, Hsw);

    dim3 gW3(32, NB2, NE);
    wswz3_kernel<<<gW3, 256, 0, stream>>>(w3, W3sw);

    ffn2_mfma_kernel<<<4 * MAXT, 512, 0, stream>>>(Hsw, W3sw, b3, counts, base_exact,
                                                   ntiles, tmap_e, tmap_m0, wts, Pb);
    combine_kernel<<<N_TOK * 128 / 256, 256, 0, stream>>>(Pb, inv, out);
}